// Round 2
// baseline (2736.376 us; speedup 1.0000x reference)
//
#include <hip/hip_runtime.h>
#include <math.h>

#define B_  2
#define T_  2048
#define C_  1024
#define NH_ 16
#define HD_ 64

// ---------------------------------------------------------------------------
// Tiled fp32 GEMM: C[MxN] = A[MxK] @ B[KxN] + bias[N]
// BM=BN=64, BK=16, 256 threads, 4x4 accumulators per thread.
// QKV_SCATTER: scatter columns into Q/K/V [B,NH,T,HD] buffers.
// ---------------------------------------------------------------------------
template<bool QKV_SCATTER>
__global__ __launch_bounds__(256)
void gemm_bias_kernel(const float* __restrict__ A, const float* __restrict__ Bm,
                      const float* __restrict__ bias, float* __restrict__ Cout,
                      int M, int N, int K,
                      float* __restrict__ q_out, float* __restrict__ k_out,
                      float* __restrict__ v_out)
{
    __shared__ float As[16][68];   // [k][m], pad 68 -> <=2-way conflicts (free)
    __shared__ float Bs[16][68];   // [k][n]

    const int tid = threadIdx.x;
    const int bm = blockIdx.y * 64;
    const int bn = blockIdx.x * 64;
    const int tx = tid & 15;       // 0..15 -> 4 output cols each
    const int ty = tid >> 4;       // 0..15 -> 4 output rows each

    float acc[4][4] = {};

    for (int k0 = 0; k0 < K; k0 += 16) {
        __syncthreads();
        // A tile 64x16 (row-major MxK), store transposed As[k][m]
        {
            const int l = tid * 4;          // 1024 elements total
            const int r = l >> 4;           // /16
            const int c = l & 15;
            const float4 av = *reinterpret_cast<const float4*>(
                &A[(size_t)(bm + r) * K + k0 + c]);
            As[c + 0][r] = av.x;
            As[c + 1][r] = av.y;
            As[c + 2][r] = av.z;
            As[c + 3][r] = av.w;
        }
        // B tile 16x64
        {
            const int l = tid * 4;
            const int r = l >> 6;           // /64
            const int c = l & 63;
            const float4 bv = *reinterpret_cast<const float4*>(
                &Bm[(size_t)(k0 + r) * N + bn + c]);
            Bs[r][c + 0] = bv.x;
            Bs[r][c + 1] = bv.y;
            Bs[r][c + 2] = bv.z;
            Bs[r][c + 3] = bv.w;
        }
        __syncthreads();

        #pragma unroll
        for (int kk = 0; kk < 16; ++kk) {
            const float4 a4 = *reinterpret_cast<const float4*>(&As[kk][ty * 4]);
            const float4 b4 = *reinterpret_cast<const float4*>(&Bs[kk][tx * 4]);
            const float a[4] = {a4.x, a4.y, a4.z, a4.w};
            const float b[4] = {b4.x, b4.y, b4.z, b4.w};
            #pragma unroll
            for (int i = 0; i < 4; ++i)
                #pragma unroll
                for (int j = 0; j < 4; ++j)
                    acc[i][j] = fmaf(a[i], b[j], acc[i][j]);
        }
    }

    #pragma unroll
    for (int i = 0; i < 4; ++i) {
        const int row = bm + ty * 4 + i;
        #pragma unroll
        for (int j = 0; j < 4; ++j) {
            const int col = bn + tx * 4 + j;
            const float v = acc[i][j] + bias[col];
            if (QKV_SCATTER) {
                const int which = col >> 10;     // col / C_
                const int cc = col & 1023;       // col % C_
                const int h = cc >> 6;           // / HD_
                const int d = cc & 63;
                const int b = row >> 11;         // / T_
                const int t = row & 2047;
                float* dst = (which == 0) ? q_out : ((which == 1) ? k_out : v_out);
                dst[(((size_t)(b * NH_ + h)) * T_ + t) * HD_ + d] = v;
            } else {
                Cout[(size_t)row * N + col] = v;
            }
        }
    }
}

// ---------------------------------------------------------------------------
// Flash-style causal attention, fp32.
// Grid: (T/64, NH, B). Block: 256 threads.
// Thread (r = tid>>2, sub = tid&3): owns q-row r, output dims [sub*16, sub*16+16).
// Q row in registers; K/V/P tiles in LDS (pad 68).
// ---------------------------------------------------------------------------
__global__ __launch_bounds__(256)
void attn_kernel(const float* __restrict__ Q, const float* __restrict__ K,
                 const float* __restrict__ V, float* __restrict__ Out)
{
    __shared__ float Ks[64][68];
    __shared__ float Vs[64][68];
    __shared__ float Ps[64][68];

    const int tid = threadIdx.x;
    const int qt  = blockIdx.x;      // q tile 0..31
    const int h   = blockIdx.y;
    const int b   = blockIdx.z;
    const int r   = tid >> 2;        // 0..63
    const int sub = tid & 3;

    const size_t bh = (size_t)(b * NH_ + h) * T_ * HD_;
    const float* Qg = Q + bh;
    const float* Kg = K + bh;
    const float* Vg = V + bh;

    // Q row -> registers, pre-scaled by 1/sqrt(HD)=0.125
    float4 qreg[16];
    {
        const float* qrow = Qg + (size_t)(qt * 64 + r) * HD_;
        #pragma unroll
        for (int i = 0; i < 16; ++i) {
            float4 t4 = reinterpret_cast<const float4*>(qrow)[i];
            t4.x *= 0.125f; t4.y *= 0.125f; t4.z *= 0.125f; t4.w *= 0.125f;
            qreg[i] = t4;
        }
    }

    float m = -1e30f, l = 0.f;
    float o[16] = {};

    for (int kt = 0; kt <= qt; ++kt) {
        __syncthreads();   // previous PV done before overwriting K/V
        // stage K,V tiles (64x64 each) via float4
        for (int i = tid; i < 64 * 16; i += 256) {
            const int rr = (i * 4) >> 6;
            const int dd = (i * 4) & 63;
            const float4 kv = *reinterpret_cast<const float4*>(
                &Kg[(size_t)(kt * 64 + rr) * HD_ + dd]);
            Ks[rr][dd + 0] = kv.x; Ks[rr][dd + 1] = kv.y;
            Ks[rr][dd + 2] = kv.z; Ks[rr][dd + 3] = kv.w;
            const float4 vv = *reinterpret_cast<const float4*>(
                &Vg[(size_t)(kt * 64 + rr) * HD_ + dd]);
            Vs[rr][dd + 0] = vv.x; Vs[rr][dd + 1] = vv.y;
            Vs[rr][dd + 2] = vv.z; Vs[rr][dd + 3] = vv.w;
        }
        __syncthreads();

        // scores for columns c = sub*16 + j
        float s[16];
        #pragma unroll
        for (int j = 0; j < 16; ++j) {
            const int c = sub * 16 + j;
            const float4* kr = reinterpret_cast<const float4*>(&Ks[c][0]);
            float accs = 0.f;
            #pragma unroll
            for (int k4 = 0; k4 < 16; ++k4) {
                const float4 kv = kr[k4];
                accs = fmaf(qreg[k4].x, kv.x, accs);
                accs = fmaf(qreg[k4].y, kv.y, accs);
                accs = fmaf(qreg[k4].z, kv.z, accs);
                accs = fmaf(qreg[k4].w, kv.w, accs);
            }
            s[j] = accs;
        }

        if (kt == qt) {   // diagonal tile: mask k>q
            #pragma unroll
            for (int j = 0; j < 16; ++j) {
                const int c = sub * 16 + j;
                if (c > r) s[j] = -1e30f;
            }
        }

        // online softmax (quad = 4 lanes per row)
        float tmax = s[0];
        #pragma unroll
        for (int j = 1; j < 16; ++j) tmax = fmaxf(tmax, s[j]);
        tmax = fmaxf(tmax, __shfl_xor(tmax, 1));
        tmax = fmaxf(tmax, __shfl_xor(tmax, 2));
        const float mnew  = fmaxf(m, tmax);
        const float alpha = __expf(m - mnew);
        float psum = 0.f;
        #pragma unroll
        for (int j = 0; j < 16; ++j) {
            const float p = __expf(s[j] - mnew);
            Ps[r][sub * 16 + j] = p;
            psum += p;
        }
        psum += __shfl_xor(psum, 1);
        psum += __shfl_xor(psum, 2);
        l = l * alpha + psum;
        m = mnew;
        #pragma unroll
        for (int d = 0; d < 16; ++d) o[d] *= alpha;
        __syncthreads();   // Ps visible to quad-mates; K/V staging done

        // PV: o[dd] += sum_c P[r][c] * V[c][sub*16+dd]
        #pragma unroll
        for (int c = 0; c < 64; ++c) {
            const float p = Ps[r][c];
            const float4* vr = reinterpret_cast<const float4*>(&Vs[c][sub * 16]);
            #pragma unroll
            for (int d4 = 0; d4 < 4; ++d4) {
                const float4 vv = vr[d4];
                o[d4 * 4 + 0] = fmaf(p, vv.x, o[d4 * 4 + 0]);
                o[d4 * 4 + 1] = fmaf(p, vv.y, o[d4 * 4 + 1]);
                o[d4 * 4 + 2] = fmaf(p, vv.z, o[d4 * 4 + 2]);
                o[d4 * 4 + 3] = fmaf(p, vv.w, o[d4 * 4 + 3]);
            }
        }
    }

    // write normalized output to [B*T, C] scratch (head-merged layout)
    const float inv_l = 1.0f / l;
    float* orow = Out + (size_t)(b * T_ + qt * 64 + r) * C_ + h * HD_ + sub * 16;
    #pragma unroll
    for (int d4 = 0; d4 < 4; ++d4) {
        float4 vv;
        vv.x = o[d4 * 4 + 0] * inv_l;
        vv.y = o[d4 * 4 + 1] * inv_l;
        vv.z = o[d4 * 4 + 2] * inv_l;
        vv.w = o[d4 * 4 + 3] * inv_l;
        reinterpret_cast<float4*>(orow)[d4] = vv;
    }
}

// ---------------------------------------------------------------------------
extern "C" void kernel_launch(void* const* d_in, const int* in_sizes, int n_in,
                              void* d_out, int out_size, void* d_ws, size_t ws_size,
                              hipStream_t stream) {
    const float* x      = (const float*)d_in[0];
    const float* W_qkv  = (const float*)d_in[1];
    const float* b_qkv  = (const float*)d_in[2];
    const float* W_proj = (const float*)d_in[3];
    const float* b_proj = (const float*)d_in[4];
    float* out = (float*)d_out;
    float* ws  = (float*)d_ws;

    const size_t nqkv = (size_t)B_ * NH_ * T_ * HD_;  // 4M elements
    float* qw   = ws;
    float* kw   = ws + nqkv;
    float* vw   = ws + 2 * nqkv;
    float* attn = ws + 3 * nqkv;                      // [B*T, C]

    const dim3 blk(256);

    // 1) QKV projection: [4096,1024] @ [1024,3072] + bias -> scatter to Q/K/V
    gemm_bias_kernel<true><<<dim3(3 * C_ / 64, B_ * T_ / 64), blk, 0, stream>>>(
        x, W_qkv, b_qkv, nullptr, B_ * T_, 3 * C_, C_, qw, kw, vw);

    // 2) causal flash attention -> attn [B*T, C]
    attn_kernel<<<dim3(T_ / 64, NH_, B_), blk, 0, stream>>>(qw, kw, vw, attn);

    // 3) output projection: [4096,1024] @ [1024,1024] + bias -> d_out
    gemm_bias_kernel<false><<<dim3(C_ / 64, B_ * T_ / 64), blk, 0, stream>>>(
        attn, W_proj, b_proj, out, B_ * T_, C_, C_, nullptr, nullptr, nullptr);
}